// Round 2
// baseline (25649.149 us; speedup 1.0000x reference)
//
#include <hip/hip_runtime.h>
#include <hip/hip_bf16.h>
#include <stdint.h>

typedef unsigned short ushort_t;
typedef unsigned int uint_t;
typedef unsigned long long ull_t;
typedef __attribute__((ext_vector_type(8))) short short8;
typedef __attribute__((ext_vector_type(4))) float floatx4;

#define T_STEPS 2048
#define BATCH 16
#define IN_F 768
#define HID 512
#define G4 2048   // 4*HID
#define NBLK 32   // workers per XCD group
#define NGRP 8    // XCD groups (redundant replicas)

// ---------------- workspace layout (bytes) ----------------
static const size_t XG_OFF   = 0;                       // xg bf16 [T][16][2048]
static const size_t XT_OFF   = 134217728ull;            // xT bf16 [32768][768]
static const size_t WIH_OFF  = XT_OFF + 50331648ull;    // wih bf16 [2048][768]
static const size_t WHH_OFF  = WIH_OFF + 3145728ull;    // whh bf16 [2048][512]
static const size_t HBUF_OFF = WHH_OFF + 2097152ull;
// within hbuf region (all zero-memset per call):
//   SLOW: 8 x u32[2][16][512] tagged  @ g*65536          (proven agent-scope)
//   FAST: 8 x u32[2][16][512] tagged  @ 524288 + g*65536 (XCD-local sc0/L2)
//   CNT : u32[8]  @ 1048576   (registration counters)
//   MASK: u32[8]  @ 1048832   (worker presence bitmasks)
static const size_t FAST_B   = 524288ull;
static const size_t CNT_B    = 1048576ull;
static const size_t MASK_B   = 1048832ull;
static const size_t HBUF_BYTES = 1048576ull + 4096ull;
static const size_t WS_NEED  = HBUF_OFF + HBUF_BYTES;

// ---------------- helpers ----------------
__device__ inline ushort_t f2bf(float f) {
  uint_t u = __float_as_uint(f);
  u = (u + 0x7FFFu + ((u >> 16) & 1u)) >> 16;
  return (ushort_t)u;
}
__device__ inline float bf2f(ushort_t h) {
  return __uint_as_float(((uint_t)h) << 16);
}
__device__ inline floatx4 mfma16(short8 a, short8 b, floatx4 c) {
  return __builtin_amdgcn_mfma_f32_16x16x32_bf16(a, b, c, 0, 0, 0);
}
__device__ inline void ld_g2l16(const void* g, void* l) {
  __builtin_amdgcn_global_load_lds(
      (const __attribute__((address_space(1))) unsigned int*)g,
      (__attribute__((address_space(3))) unsigned int*)l, 16, 0, 0);
}
__device__ inline float sigf(float x) {
  float e = __expf(-x);
  return __fdividef(1.0f, 1.0f + e);
}
__device__ inline float tanhf_fast(float x) {
  x = fminf(fmaxf(x, -15.0f), 15.0f);
  float e = __expf(2.0f * x);
  return __fdividef(e - 1.0f, e + 1.0f);
}
// agent-scope (IF$-coherent) accesses — the PROVEN transport from the 4836us kernel
__device__ inline ull_t cload64(const ull_t* p) {
  return __hip_atomic_load(p, __ATOMIC_RELAXED, __HIP_MEMORY_SCOPE_AGENT);
}
__device__ inline uint_t cload32(const uint_t* p) {
  return __hip_atomic_load(p, __ATOMIC_RELAXED, __HIP_MEMORY_SCOPE_AGENT);
}
__device__ inline void cstore32(uint_t* p, uint_t v) {
  __hip_atomic_store(p, v, __ATOMIC_RELAXED, __HIP_MEMORY_SCOPE_AGENT);
}

// ---------------- phase 0: converts ----------------
__global__ __launch_bounds__(256) void conv_x_k(const float4* __restrict__ x,
                                                ushort_t* __restrict__ xT) {
  uint_t idx = blockIdx.x * 256u + threadIdx.x;  // < 6291456 exactly
  float4 v = x[idx];
  uint_t e = idx * 4u;
  uint_t k = e % 768u;
  uint_t rin = e / 768u;          // b*2048 + t
  uint_t b = rin >> 11, t = rin & 2047u;
  size_t o = (size_t)(t * 16u + b) * 768u + k;
  ushort4 r;
  r.x = f2bf(v.x); r.y = f2bf(v.y); r.z = f2bf(v.z); r.w = f2bf(v.w);
  *(ushort4*)(xT + o) = r;
}

__global__ __launch_bounds__(256) void conv_w_k(const float4* __restrict__ src,
                                                ushort_t* __restrict__ dst, uint_t n4) {
  uint_t idx = blockIdx.x * 256u + threadIdx.x;
  if (idx >= n4) return;
  float4 v = src[idx];
  ushort4 r;
  r.x = f2bf(v.x); r.y = f2bf(v.y); r.z = f2bf(v.z); r.w = f2bf(v.w);
  *(ushort4*)(dst + (size_t)idx * 4u) = r;
}

// ---------------- phase 1: xg = xT @ wih^T + bias, bf16 out ----------------
__global__ __launch_bounds__(256) void gemm_xg(const ushort_t* __restrict__ A,
                                               const ushort_t* __restrict__ Bw,
                                               const float* __restrict__ bih,
                                               const float* __restrict__ bhh,
                                               ushort_t* __restrict__ xg) {
  __shared__ __align__(16) ushort_t Asm[128 * 64];
  __shared__ __align__(16) ushort_t Bsm[128 * 64];
  const int tid = threadIdx.x;
  const int w = tid >> 6, l = tid & 63;
  const int m_ = l & 15, q = l >> 4;
  const int lr = l >> 3, lc = l & 7;
  const int nt = blockIdx.x, mt = blockIdx.y;
  const int wr = (w >> 1) * 64, wc = (w & 1) * 64;

  floatx4 acc[4][4];
  for (int i = 0; i < 4; i++)
    for (int j = 0; j < 4; j++) acc[i][j] = (floatx4){0.f, 0.f, 0.f, 0.f};

  for (int it = 0; it < 12; ++it) {
    const int K0 = it * 64;
    for (int p = 0; p < 4; p++) {
      int row = w * 32 + p * 8 + lr;
      int c = lc ^ lr;
      ld_g2l16(A + (size_t)(mt * 128 + row) * 768 + K0 + c * 8,
               Asm + (size_t)(w * 32 + p * 8) * 64);
      ld_g2l16(Bw + (size_t)(nt * 128 + row) * 768 + K0 + c * 8,
               Bsm + (size_t)(w * 32 + p * 8) * 64);
    }
    __syncthreads();
    short8 af[2][4], bfr[2][4];
    for (int kk = 0; kk < 2; kk++) {
      int chunk = kk * 4 + q;
      for (int rt = 0; rt < 4; rt++) {
        int row = wr + rt * 16 + m_;
        af[kk][rt] = *(const short8*)(Asm + (size_t)row * 64 + (size_t)(chunk ^ (row & 7)) * 8);
        int col = wc + rt * 16 + m_;
        bfr[kk][rt] = *(const short8*)(Bsm + (size_t)col * 64 + (size_t)(chunk ^ (col & 7)) * 8);
      }
    }
    for (int kk = 0; kk < 2; kk++)
      for (int rt = 0; rt < 4; rt++)
        for (int ct = 0; ct < 4; ct++)
          acc[rt][ct] = mfma16(af[kk][rt], bfr[kk][ct], acc[rt][ct]);
    __syncthreads();
  }
  for (int ct = 0; ct < 4; ct++) {
    int gcol = nt * 128 + wc + ct * 16 + m_;
    float bias = bih[gcol] + bhh[gcol];
    for (int rt = 0; rt < 4; rt++) {
      int growb = mt * 128 + wr + rt * 16 + q * 4;
      for (int r = 0; r < 4; r++)
        xg[(size_t)(growb + r) * G4 + gcol] = f2bf(acc[rt][ct][r] + bias);
    }
  }
}

// ---------------- phase 2: persistent recurrent kernel ----------------
// 256 blocks x 256 threads (static 51KB LDS — proven launch config). Block reads
// HW_REG_XCC_ID, joins its XCD's group; default round-robin dispatch gives 32
// blocks/XCD. Completeness is VERIFIED via a presence bitmask: incomplete
// groups exit (~0.6ms) without writing out; pigeonhole guarantees >=1 complete
// group, and every complete group writes the whole out (bit-identical).
// Transport per step = FAST (sc0, XCD-local L2, ~200cy RTT) with bounded budget,
// falling back to the PROVEN agent-scope path. Fast-accept requires exact
// 16-row tag match -> can never yield wrong data, only a fallback. 8 consecutive
// fast failures disable the fast path (wave-local).
__global__ __launch_bounds__(256, 1) void lstm_rec(const ushort_t* __restrict__ xg,
                                                   const ushort_t* __restrict__ whh,
                                                   uint_t* hbuf, float* __restrict__ out) {
  const int tid = threadIdx.x;
  const int w = tid >> 6, l = tid & 63;
  const int m_ = l & 15, q = l >> 4;

  __shared__ uint_t s_slot, s_xcc, s_dead;
  if (tid == 0) {
    uint_t xcc = __builtin_amdgcn_s_getreg(63508) & 7u;  // hwreg(HW_REG_XCC_ID=20,0,32)
    s_xcc = xcc;
    s_dead = 0u;
    uint_t slot = atomicAdd(hbuf + (CNT_B / 4) + xcc, 1u);
    s_slot = slot;
    if (slot < (uint_t)NBLK)
      atomicOr(hbuf + (MASK_B / 4) + xcc, 1u << slot);
  }
  __syncthreads();
  const uint_t xcc = s_xcc;
  const int j = (int)s_slot;                       // owned h cols [16j,16j+16)
  if (j >= NBLK) return;                           // surplus block on this XCD

  // ---- verify group completeness (runtime check of the placement assumption)
  if (tid == 0) {
    uint_t got = 0u;
    for (int it = 0; it < 2048; ++it) {
      if (cload32(hbuf + (MASK_B / 4) + xcc) == 0xFFFFFFFFu) { got = 1u; break; }
    }
    s_dead = got ? 0u : 1u;
  }
  __syncthreads();
  if (s_dead) return;                              // incomplete group: exit, no out

  uint_t* slowp = hbuf + (size_t)xcc * 16384u;     // group-private slow tagged dbuf
  const ull_t* slow_ull = (const ull_t*)slowp;
  uint_t* fastp = hbuf + (FAST_B / 4) + (size_t)xcc * 16384u;
  const ull_t fastb = (ull_t)(uintptr_t)fastp;

  // bfrag[g][kk]: B[k][n], n = g*512 + j*16 + m_, k = w*128 + kk*32 + q*8 + jj
  short8 bfrag[4][4];
  for (int g = 0; g < 4; g++) {
    const ushort_t* wrow = whh + (size_t)(g * HID + j * 16 + m_) * HID + w * 128 + q * 8;
    for (int kk = 0; kk < 4; kk++) bfrag[g][kk] = *(const short8*)(wrow + kk * 32);
  }

  const int erow = tid >> 4, ecol = tid & 15;  // epilogue ownership (batch row, h col)
  float c_reg = 0.f;
  __shared__ __align__(16) ushort_t hsm[BATCH * HID];   // 16 KB, XOR-swizzled chunks
  __shared__ float gsm[2][4][4][16][17];                // [par][wave][gate][row][col]

  // epilogue xg: idx(t,g) = (t*16 + erow)*2048 + g*512 + j*16 + ecol
  const ushort_t* xgp = xg + (size_t)erow * G4 + j * 16 + ecol;
  ushort_t xgv[4];
  for (int g = 0; g < 4; g++) xgv[g] = xgp[g * HID];

  // stage: wave w loads tagged cols [128w,128w+128) of all 16 rows.
  // u64 idx of lane l, row r: sbase + r*256 (row stride 512 u32 = 2048 B).
  const int sbase = w * 64 + l;
  uint_t slowGuard = 0;
  int failStreak = 0;
  bool fastEn = true;
  bool dead = false;

  for (int t = 0; t < T_STEPS; t++) {
    // prefetch next step's xg (plain cached loads, independent of h)
    ushort_t xgn[4];
    {
      int tt = (t + 1 < T_STEPS) ? (t + 1) : t;
      const ushort_t* p = xgp + (size_t)tt * 16 * G4;
      for (int g = 0; g < 4; g++) xgn[g] = p[g * HID];
    }

    ull_t vals[16];
    const ull_t expect = ((ull_t)(uint_t)(t & 0xffff) << 16) |
                         ((ull_t)(uint_t)(t & 0xffff) << 48);
    bool have = false;

    // ---- FAST path: sc0 loads against XCD-local L2 (budgeted, validated) ----
    if (fastEn && !dead) {
      const ull_t fbase = fastb + (ull_t)(t & 1) * 32768ull + (ull_t)sbase * 8ull;
      // sparse pre-spin: lane watches row (l&15) of its own col-pair; the wave's
      // 64 lanes sample all 8 producer blocks of its slice.
      const ull_t sa = fbase + (ull_t)(l & 15) * 2048ull;
      int fb = 96;
      while (fb > 0) {
        ull_t sv;
        asm volatile("global_load_dwordx2 %0, %1, off sc0" : "=v"(sv) : "v"(sa));
        asm volatile("s_waitcnt vmcnt(0)" : "+v"(sv));
        --fb;
        if (!__all((int)((sv & 0xFFFF0000FFFF0000ull) == expect))) continue;
#pragma unroll
        for (int r = 0; r < 16; r++)
          asm volatile("global_load_dwordx2 %0, %1, off sc0"
                       : "=v"(vals[r]) : "v"(fbase + (ull_t)r * 2048ull));
        asm volatile("s_waitcnt vmcnt(0)"
                     : "+v"(vals[0]), "+v"(vals[1]), "+v"(vals[2]), "+v"(vals[3]),
                       "+v"(vals[4]), "+v"(vals[5]), "+v"(vals[6]), "+v"(vals[7]),
                       "+v"(vals[8]), "+v"(vals[9]), "+v"(vals[10]), "+v"(vals[11]),
                       "+v"(vals[12]), "+v"(vals[13]), "+v"(vals[14]), "+v"(vals[15]));
        bool okv = true;
#pragma unroll
        for (int r = 0; r < 16; r++)
          okv &= ((vals[r] & 0xFFFF0000FFFF0000ull) == expect);
        if (__all((int)okv)) { have = true; break; }
        fb -= 4;
      }
      if (have) failStreak = 0;
      else if (++failStreak >= 8) fastEn = false;
    }

    // ---- SLOW path: proven agent-scope transport ----
    if (!have && !dead) {
      const ull_t* gp = slow_ull + (size_t)(t & 1) * 4096 + sbase;
      for (;;) {
        for (int r = 0; r < 16; r++) vals[r] = cload64(gp + r * 256);
        bool ok = true;
        for (int r = 0; r < 16; r++)
          ok &= ((vals[r] & 0xFFFF0000FFFF0000ull) == expect);
        if (__all((int)ok)) break;
        if (++slowGuard > (1u << 20)) { dead = true; if (l == 0) s_dead = 1u; break; }
      }
    }
    if (dead) {
#pragma unroll
      for (int r = 0; r < 16; r++) vals[r] = 0;   // keep lockstep, never publish
    }

    // ---- strip tags, write own hsm slice (intra-wave only) ----
    // value pair = cols (128w + 2l, +1) of row r; chunk = 16w + (l>>2),
    // slot = chunk ^ (r&7), u32 offset (l&3) within 16B slot. Conflict-free.
    {
      const int chunk = w * 16 + (l >> 2);
      for (int r = 0; r < 16; r++) {
        uint_t pk = (uint_t)(vals[r] & 0xffffu) | ((uint_t)(vals[r] >> 32) << 16);
        int slot = chunk ^ (r & 7);
        *(uint_t*)(hsm + (size_t)r * HID + slot * 8 + (l & 3) * 2) = pk;
      }
    }
    // ---- MFMA: A row m_, chunks 16w + kk*4 + q (own slice; in-wave ordering) ----
    floatx4 acc[4];
    for (int g = 0; g < 4; g++) acc[g] = (floatx4){0.f, 0.f, 0.f, 0.f};
    for (int kk = 0; kk < 4; kk++) {
      int slot = (w * 16 + kk * 4 + q) ^ (m_ & 7);
      short8 a = *(const short8*)(hsm + (size_t)m_ * HID + slot * 8);
      for (int g = 0; g < 4; g++) acc[g] = mfma16(a, bfrag[g][kk], acc[g]);
    }
    // ---- partial exchange ----
    const int par = t & 1;
    for (int g = 0; g < 4; g++)
      for (int r = 0; r < 4; r++) gsm[par][w][g][q * 4 + r][m_] = acc[g][r];
    __syncthreads();
    const bool blkdead = (s_dead != 0u);   // set pre-barrier by any dying wave
    if (blkdead) dead = true;

    float gate[4];
    for (int g = 0; g < 4; g++) {
      float s = gsm[par][0][g][erow][ecol] + gsm[par][1][g][erow][ecol] +
                gsm[par][2][g][erow][ecol] + gsm[par][3][g][erow][ecol];
      gate[g] = s + bf2f(xgv[g]);
    }
    float iv = sigf(gate[0]);
    float fv = sigf(gate[1]);
    float gv = tanhf_fast(gate[2]);
    float ov = sigf(gate[3]);
    float c = fv * c_reg + iv * gv;
    c_reg = c;
    float h = ov * tanhf_fast(c);

    if (!blkdead) {
      // ---- dual publish tagged h(t+1): fast (sc0/L2) then slow (agent) ----
      uint_t pv = ((uint_t)((t + 1) & 0xffff) << 16) | (uint_t)f2bf(h);
      size_t po = (size_t)((t + 1) & 1) * 8192 + (size_t)erow * HID + j * 16 + ecol;
      ull_t fa = fastb + (ull_t)po * 4ull;
      asm volatile("global_store_dword %0, %1, off sc0" :: "v"(fa), "v"(pv) : "memory");
      cstore32(slowp + po, pv);
      // off the critical path; all complete groups write identical values
      out[(size_t)erow * (T_STEPS * HID) + (size_t)t * HID + j * 16 + ecol] = h;
    }
    for (int g = 0; g < 4; g++) xgv[g] = xgn[g];
  }
}

// ---------------- host ----------------
extern "C" void kernel_launch(void* const* d_in, const int* in_sizes, int n_in,
                              void* d_out, int out_size, void* d_ws, size_t ws_size,
                              hipStream_t stream) {
  (void)in_sizes; (void)n_in; (void)out_size;
  if (ws_size < WS_NEED) return;

  const float* x   = (const float*)d_in[0];
  const float* wih = (const float*)d_in[1];
  const float* whh = (const float*)d_in[2];
  const float* bih = (const float*)d_in[3];
  const float* bhh = (const float*)d_in[4];
  float* out = (float*)d_out;
  char* ws = (char*)d_ws;

  ushort_t* xg_b   = (ushort_t*)(ws + XG_OFF);
  ushort_t* xT_b   = (ushort_t*)(ws + XT_OFF);
  ushort_t* wih_b  = (ushort_t*)(ws + WIH_OFF);
  ushort_t* whh_b  = (ushort_t*)(ws + WHH_OFF);
  uint_t*   hbuf   = (uint_t*)(ws + HBUF_OFF);

  // zero tagged h double-buffers (slow+fast: tag 0 == h(0) == 0), counters, masks
  hipMemsetAsync(ws + HBUF_OFF, 0, HBUF_BYTES, stream);

  conv_x_k<<<24576, 256, 0, stream>>>((const float4*)x, xT_b);
  conv_w_k<<<1536, 256, 0, stream>>>((const float4*)wih, wih_b, 393216u);
  conv_w_k<<<1024, 256, 0, stream>>>((const float4*)whh, whh_b, 262144u);
  gemm_xg<<<dim3(16, 256), 256, 0, stream>>>(xT_b, wih_b, bih, bhh, xg_b);
  lstm_rec<<<256, 256, 0, stream>>>(xg_b, whh_b, hbuf, out);
}

// Round 3
// 24187.927 us; speedup vs baseline: 1.0604x; 1.0604x over previous
//
#include <hip/hip_runtime.h>
#include <hip/hip_bf16.h>
#include <stdint.h>

typedef unsigned short ushort_t;
typedef unsigned int uint_t;
typedef unsigned long long ull_t;
typedef __attribute__((ext_vector_type(8))) short short8;
typedef __attribute__((ext_vector_type(4))) float floatx4;

#define T_STEPS 2048
#define BATCH 16
#define IN_F 768
#define HID 512
#define G4 2048   // 4*HID
#define NBLK 32   // workers in the elected XCD group
#define NGRP 8    // XCD groups (candidates; exactly ONE is elected)

// ---------------- workspace layout (bytes) ----------------
static const size_t XG_OFF   = 0;                       // xg bf16 [T][16][2048]
static const size_t XT_OFF   = 134217728ull;            // xT bf16 [32768][768]
static const size_t WIH_OFF  = XT_OFF + 50331648ull;    // wih bf16 [2048][768]
static const size_t WHH_OFF  = WIH_OFF + 3145728ull;    // whh bf16 [2048][512]
static const size_t HBUF_OFF = WHH_OFF + 2097152ull;
// within hbuf region (all zero-memset per call):
//   SLOW: 8 x u32[2][16][512] tagged  @ g*65536          (proven agent-scope)
//   FAST: 8 x u32[2][16][512] tagged  @ 524288 + g*65536 (XCD-local sc0/L2)
//   CNT : u32[8]  @ 1048576   (registration counters)
//   MASK: u32[8]  @ 1048832   (worker presence bitmasks)
//   CLAIM: u32   @ 1049088    (group election word)
static const size_t FAST_B   = 524288ull;
static const size_t CNT_B    = 1048576ull;
static const size_t MASK_B   = 1048832ull;
static const size_t CLAIM_B  = 1049088ull;
static const size_t HBUF_BYTES = 1048576ull + 4096ull;
static const size_t WS_NEED  = HBUF_OFF + HBUF_BYTES;

// ---------------- helpers ----------------
__device__ inline ushort_t f2bf(float f) {
  uint_t u = __float_as_uint(f);
  u = (u + 0x7FFFu + ((u >> 16) & 1u)) >> 16;
  return (ushort_t)u;
}
__device__ inline float bf2f(ushort_t h) {
  return __uint_as_float(((uint_t)h) << 16);
}
__device__ inline floatx4 mfma16(short8 a, short8 b, floatx4 c) {
  return __builtin_amdgcn_mfma_f32_16x16x32_bf16(a, b, c, 0, 0, 0);
}
__device__ inline void ld_g2l16(const void* g, void* l) {
  __builtin_amdgcn_global_load_lds(
      (const __attribute__((address_space(1))) unsigned int*)g,
      (__attribute__((address_space(3))) unsigned int*)l, 16, 0, 0);
}
__device__ inline float sigf(float x) {
  float e = __expf(-x);
  return __fdividef(1.0f, 1.0f + e);
}
__device__ inline float tanhf_fast(float x) {
  x = fminf(fmaxf(x, -15.0f), 15.0f);
  float e = __expf(2.0f * x);
  return __fdividef(e - 1.0f, e + 1.0f);
}
// agent-scope (IF$-coherent) accesses — the PROVEN transport from the 4836us kernel
__device__ inline ull_t cload64(const ull_t* p) {
  return __hip_atomic_load(p, __ATOMIC_RELAXED, __HIP_MEMORY_SCOPE_AGENT);
}
__device__ inline uint_t cload32(const uint_t* p) {
  return __hip_atomic_load(p, __ATOMIC_RELAXED, __HIP_MEMORY_SCOPE_AGENT);
}
__device__ inline void cstore32(uint_t* p, uint_t v) {
  __hip_atomic_store(p, v, __ATOMIC_RELAXED, __HIP_MEMORY_SCOPE_AGENT);
}

// ---------------- phase 0: converts ----------------
__global__ __launch_bounds__(256) void conv_x_k(const float4* __restrict__ x,
                                                ushort_t* __restrict__ xT) {
  uint_t idx = blockIdx.x * 256u + threadIdx.x;  // < 6291456 exactly
  float4 v = x[idx];
  uint_t e = idx * 4u;
  uint_t k = e % 768u;
  uint_t rin = e / 768u;          // b*2048 + t
  uint_t b = rin >> 11, t = rin & 2047u;
  size_t o = (size_t)(t * 16u + b) * 768u + k;
  ushort4 r;
  r.x = f2bf(v.x); r.y = f2bf(v.y); r.z = f2bf(v.z); r.w = f2bf(v.w);
  *(ushort4*)(xT + o) = r;
}

__global__ __launch_bounds__(256) void conv_w_k(const float4* __restrict__ src,
                                                ushort_t* __restrict__ dst, uint_t n4) {
  uint_t idx = blockIdx.x * 256u + threadIdx.x;
  if (idx >= n4) return;
  float4 v = src[idx];
  ushort4 r;
  r.x = f2bf(v.x); r.y = f2bf(v.y); r.z = f2bf(v.z); r.w = f2bf(v.w);
  *(ushort4*)(dst + (size_t)idx * 4u) = r;
}

// ---------------- phase 1: xg = xT @ wih^T + bias, bf16 out ----------------
__global__ __launch_bounds__(256) void gemm_xg(const ushort_t* __restrict__ A,
                                               const ushort_t* __restrict__ Bw,
                                               const float* __restrict__ bih,
                                               const float* __restrict__ bhh,
                                               ushort_t* __restrict__ xg) {
  __shared__ __align__(16) ushort_t Asm[128 * 64];
  __shared__ __align__(16) ushort_t Bsm[128 * 64];
  const int tid = threadIdx.x;
  const int w = tid >> 6, l = tid & 63;
  const int m_ = l & 15, q = l >> 4;
  const int lr = l >> 3, lc = l & 7;
  const int nt = blockIdx.x, mt = blockIdx.y;
  const int wr = (w >> 1) * 64, wc = (w & 1) * 64;

  floatx4 acc[4][4];
  for (int i = 0; i < 4; i++)
    for (int j = 0; j < 4; j++) acc[i][j] = (floatx4){0.f, 0.f, 0.f, 0.f};

  for (int it = 0; it < 12; ++it) {
    const int K0 = it * 64;
    for (int p = 0; p < 4; p++) {
      int row = w * 32 + p * 8 + lr;
      int c = lc ^ lr;
      ld_g2l16(A + (size_t)(mt * 128 + row) * 768 + K0 + c * 8,
               Asm + (size_t)(w * 32 + p * 8) * 64);
      ld_g2l16(Bw + (size_t)(nt * 128 + row) * 768 + K0 + c * 8,
               Bsm + (size_t)(w * 32 + p * 8) * 64);
    }
    __syncthreads();
    short8 af[2][4], bfr[2][4];
    for (int kk = 0; kk < 2; kk++) {
      int chunk = kk * 4 + q;
      for (int rt = 0; rt < 4; rt++) {
        int row = wr + rt * 16 + m_;
        af[kk][rt] = *(const short8*)(Asm + (size_t)row * 64 + (size_t)(chunk ^ (row & 7)) * 8);
        int col = wc + rt * 16 + m_;
        bfr[kk][rt] = *(const short8*)(Bsm + (size_t)col * 64 + (size_t)(chunk ^ (col & 7)) * 8);
      }
    }
    for (int kk = 0; kk < 2; kk++)
      for (int rt = 0; rt < 4; rt++)
        for (int ct = 0; ct < 4; ct++)
          acc[rt][ct] = mfma16(af[kk][rt], bfr[kk][ct], acc[rt][ct]);
    __syncthreads();
  }
  for (int ct = 0; ct < 4; ct++) {
    int gcol = nt * 128 + wc + ct * 16 + m_;
    float bias = bih[gcol] + bhh[gcol];
    for (int rt = 0; rt < 4; rt++) {
      int growb = mt * 128 + wr + rt * 16 + q * 4;
      for (int r = 0; r < 4; r++)
        xg[(size_t)(growb + r) * G4 + gcol] = f2bf(acc[rt][ct][r] + bias);
    }
  }
}

// ---------------- phase 2: persistent recurrent kernel ----------------
// 256 blocks x 256 threads. Block reads HW_REG_XCC_ID and registers in its
// XCD's group. Pigeonhole (256 blocks / 8 XCDs / 32 slots) guarantees >=1
// COMPLETE group (verified via presence bitmask). Complete groups race an
// atomicCAS election; the ONE winning group (32 blocks, all on one XCD) runs
// the recurrence; everyone else exits within ~us (incomplete groups time out
// their completeness poll in ~0.8ms on otherwise-idle CUs). Single active
// group => no fabric contention (round-2 lesson: 8 replicas congested IF$ 8x).
// Transport per step = FAST (sc0 = L1-bypass, coherent in the winner XCD's
// shared L2, ~200cy RTT) with bounded budget, falling back to the PROVEN
// agent-scope path. Fast-accept requires exact 16-row tag match -> can never
// yield wrong data, only a fallback. 8 consecutive fast failures disable the
// fast path (wave-local). Worst case ~= baseline 4.8ms + ~0.1ms.
__global__ __launch_bounds__(256, 1) void lstm_rec(const ushort_t* __restrict__ xg,
                                                   const ushort_t* __restrict__ whh,
                                                   uint_t* hbuf, float* __restrict__ out) {
  const int tid = threadIdx.x;
  const int w = tid >> 6, l = tid & 63;
  const int m_ = l & 15, q = l >> 4;

  __shared__ uint_t s_slot, s_xcc, s_dead, s_win;
  if (tid == 0) {
    uint_t xcc = __builtin_amdgcn_s_getreg(63508) & 7u;  // hwreg(HW_REG_XCC_ID=20,0,32)
    s_xcc = xcc;
    s_dead = 0u;
    uint_t slot = atomicAdd(hbuf + (CNT_B / 4) + xcc, 1u);
    s_slot = slot;
    if (slot < (uint_t)NBLK)
      atomicOr(hbuf + (MASK_B / 4) + xcc, 1u << slot);
  }
  __syncthreads();
  const uint_t xcc = s_xcc;
  const int j = (int)s_slot;                       // owned h cols [16j,16j+16)
  if (j >= NBLK) return;                           // surplus block on this XCD

  // ---- verify group completeness (runtime check of the placement assumption)
  if (tid == 0) {
    uint_t got = 0u;
    for (int it = 0; it < 2048; ++it) {
      if (cload32(hbuf + (MASK_B / 4) + xcc) == 0xFFFFFFFFu) { got = 1u; break; }
    }
    s_dead = got ? 0u : 1u;
    if (got) {
      // ---- election: first complete group to CAS owns the recurrence ----
      uint_t old = atomicCAS(hbuf + (CLAIM_B / 4), 0u, xcc + 1u);
      uint_t tag = (old == 0u) ? (xcc + 1u) : old;   // claim is write-once
      s_win = (tag == xcc + 1u) ? 1u : 0u;
    } else {
      s_win = 0u;
    }
  }
  __syncthreads();
  if (s_dead || !s_win) return;                    // not the elected group: exit

  uint_t* slowp = hbuf + (size_t)xcc * 16384u;     // group-private slow tagged dbuf
  const ull_t* slow_ull = (const ull_t*)slowp;
  uint_t* fastp = hbuf + (FAST_B / 4) + (size_t)xcc * 16384u;
  const ull_t fastb = (ull_t)(uintptr_t)fastp;

  // bfrag[g][kk]: B[k][n], n = g*512 + j*16 + m_, k = w*128 + kk*32 + q*8 + jj
  short8 bfrag[4][4];
  for (int g = 0; g < 4; g++) {
    const ushort_t* wrow = whh + (size_t)(g * HID + j * 16 + m_) * HID + w * 128 + q * 8;
    for (int kk = 0; kk < 4; kk++) bfrag[g][kk] = *(const short8*)(wrow + kk * 32);
  }

  const int erow = tid >> 4, ecol = tid & 15;  // epilogue ownership (batch row, h col)
  float c_reg = 0.f;
  __shared__ __align__(16) ushort_t hsm[BATCH * HID];   // 16 KB, XOR-swizzled chunks
  __shared__ float gsm[2][4][4][16][17];                // [par][wave][gate][row][col]

  // epilogue xg: idx(t,g) = (t*16 + erow)*2048 + g*512 + j*16 + ecol
  const ushort_t* xgp = xg + (size_t)erow * G4 + j * 16 + ecol;
  ushort_t xgv[4];
  for (int g = 0; g < 4; g++) xgv[g] = xgp[g * HID];

  // stage: wave w loads tagged cols [128w,128w+128) of all 16 rows.
  // u64 idx of lane l, row r: sbase + r*256 (row stride 512 u32 = 2048 B).
  const int sbase = w * 64 + l;
  uint_t slowGuard = 0;
  int failStreak = 0;
  bool fastEn = true;
  bool dead = false;

  for (int t = 0; t < T_STEPS; t++) {
    // prefetch next step's xg (plain cached loads, independent of h)
    ushort_t xgn[4];
    {
      int tt = (t + 1 < T_STEPS) ? (t + 1) : t;
      const ushort_t* p = xgp + (size_t)tt * 16 * G4;
      for (int g = 0; g < 4; g++) xgn[g] = p[g * HID];
    }

    ull_t vals[16];
    const ull_t expect = ((ull_t)(uint_t)(t & 0xffff) << 16) |
                         ((ull_t)(uint_t)(t & 0xffff) << 48);
    bool have = false;

    // ---- FAST path: sc0 loads against the winner XCD's L2 (budgeted, validated)
    if (fastEn && !dead) {
      const ull_t fbase = fastb + (ull_t)(t & 1) * 32768ull + (ull_t)sbase * 8ull;
      // sparse pre-spin: lane watches row (l&15) of its own col-pair; the wave's
      // 64 lanes sample all 8 producer blocks of its slice. ~512B/blk/iter.
      const ull_t sa = fbase + (ull_t)(l & 15) * 2048ull;
      int fb = 96;
      while (fb > 0) {
        ull_t sv;
        asm volatile("global_load_dwordx2 %0, %1, off sc0" : "=v"(sv) : "v"(sa));
        asm volatile("s_waitcnt vmcnt(0)" : "+v"(sv));
        --fb;
        if (!__all((int)((sv & 0xFFFF0000FFFF0000ull) == expect))) continue;
#pragma unroll
        for (int r = 0; r < 16; r++)
          asm volatile("global_load_dwordx2 %0, %1, off sc0"
                       : "=v"(vals[r]) : "v"(fbase + (ull_t)r * 2048ull));
        asm volatile("s_waitcnt vmcnt(0)"
                     : "+v"(vals[0]), "+v"(vals[1]), "+v"(vals[2]), "+v"(vals[3]),
                       "+v"(vals[4]), "+v"(vals[5]), "+v"(vals[6]), "+v"(vals[7]),
                       "+v"(vals[8]), "+v"(vals[9]), "+v"(vals[10]), "+v"(vals[11]),
                       "+v"(vals[12]), "+v"(vals[13]), "+v"(vals[14]), "+v"(vals[15]));
        bool okv = true;
#pragma unroll
        for (int r = 0; r < 16; r++)
          okv &= ((vals[r] & 0xFFFF0000FFFF0000ull) == expect);
        if (__all((int)okv)) { have = true; break; }
        fb -= 4;
      }
      if (have) failStreak = 0;
      else if (++failStreak >= 8) fastEn = false;
    }

    // ---- SLOW path: proven agent-scope transport ----
    if (!have && !dead) {
      const ull_t* gp = slow_ull + (size_t)(t & 1) * 4096 + sbase;
      for (;;) {
        for (int r = 0; r < 16; r++) vals[r] = cload64(gp + r * 256);
        bool ok = true;
        for (int r = 0; r < 16; r++)
          ok &= ((vals[r] & 0xFFFF0000FFFF0000ull) == expect);
        if (__all((int)ok)) break;
        if (++slowGuard > (1u << 20)) { dead = true; if (l == 0) s_dead = 1u; break; }
      }
    }
    if (dead) {
#pragma unroll
      for (int r = 0; r < 16; r++) vals[r] = 0;   // keep lockstep, never publish
    }

    // ---- strip tags, write own hsm slice (intra-wave only) ----
    // value pair = cols (128w + 2l, +1) of row r; chunk = 16w + (l>>2),
    // slot = chunk ^ (r&7), u32 offset (l&3) within 16B slot. Conflict-free.
    {
      const int chunk = w * 16 + (l >> 2);
      for (int r = 0; r < 16; r++) {
        uint_t pk = (uint_t)(vals[r] & 0xffffu) | ((uint_t)(vals[r] >> 32) << 16);
        int slot = chunk ^ (r & 7);
        *(uint_t*)(hsm + (size_t)r * HID + slot * 8 + (l & 3) * 2) = pk;
      }
    }
    // ---- MFMA: A row m_, chunks 16w + kk*4 + q (own slice; in-wave ordering) ----
    floatx4 acc[4];
    for (int g = 0; g < 4; g++) acc[g] = (floatx4){0.f, 0.f, 0.f, 0.f};
    for (int kk = 0; kk < 4; kk++) {
      int slot = (w * 16 + kk * 4 + q) ^ (m_ & 7);
      short8 a = *(const short8*)(hsm + (size_t)m_ * HID + slot * 8);
      for (int g = 0; g < 4; g++) acc[g] = mfma16(a, bfrag[g][kk], acc[g]);
    }
    // ---- partial exchange ----
    const int par = t & 1;
    for (int g = 0; g < 4; g++)
      for (int r = 0; r < 4; r++) gsm[par][w][g][q * 4 + r][m_] = acc[g][r];
    __syncthreads();
    const bool blkdead = (s_dead != 0u);   // set pre-barrier by any dying wave
    if (blkdead) dead = true;

    float gate[4];
    for (int g = 0; g < 4; g++) {
      float s = gsm[par][0][g][erow][ecol] + gsm[par][1][g][erow][ecol] +
                gsm[par][2][g][erow][ecol] + gsm[par][3][g][erow][ecol];
      gate[g] = s + bf2f(xgv[g]);
    }
    float iv = sigf(gate[0]);
    float fv = sigf(gate[1]);
    float gv = tanhf_fast(gate[2]);
    float ov = sigf(gate[3]);
    float c = fv * c_reg + iv * gv;
    c_reg = c;
    float h = ov * tanhf_fast(c);

    if (!blkdead) {
      // ---- dual publish tagged h(t+1): fast (sc0/L2) then slow (agent) ----
      uint_t pv = ((uint_t)((t + 1) & 0xffff) << 16) | (uint_t)f2bf(h);
      size_t po = (size_t)((t + 1) & 1) * 8192 + (size_t)erow * HID + j * 16 + ecol;
      ull_t fa = fastb + (ull_t)po * 4ull;
      asm volatile("global_store_dword %0, %1, off sc0" :: "v"(fa), "v"(pv) : "memory");
      cstore32(slowp + po, pv);
      // off the critical path; only the elected group writes out
      out[(size_t)erow * (T_STEPS * HID) + (size_t)t * HID + j * 16 + ecol] = h;
    }
    for (int g = 0; g < 4; g++) xgv[g] = xgn[g];
  }
}

// ---------------- host ----------------
extern "C" void kernel_launch(void* const* d_in, const int* in_sizes, int n_in,
                              void* d_out, int out_size, void* d_ws, size_t ws_size,
                              hipStream_t stream) {
  (void)in_sizes; (void)n_in; (void)out_size;
  if (ws_size < WS_NEED) return;

  const float* x   = (const float*)d_in[0];
  const float* wih = (const float*)d_in[1];
  const float* whh = (const float*)d_in[2];
  const float* bih = (const float*)d_in[3];
  const float* bhh = (const float*)d_in[4];
  float* out = (float*)d_out;
  char* ws = (char*)d_ws;

  ushort_t* xg_b   = (ushort_t*)(ws + XG_OFF);
  ushort_t* xT_b   = (ushort_t*)(ws + XT_OFF);
  ushort_t* wih_b  = (ushort_t*)(ws + WIH_OFF);
  ushort_t* whh_b  = (ushort_t*)(ws + WHH_OFF);
  uint_t*   hbuf   = (uint_t*)(ws + HBUF_OFF);

  // zero tagged h double-buffers (slow+fast: tag 0 == h(0) == 0), counters,
  // masks, and the election word
  hipMemsetAsync(ws + HBUF_OFF, 0, HBUF_BYTES, stream);

  conv_x_k<<<24576, 256, 0, stream>>>((const float4*)x, xT_b);
  conv_w_k<<<1536, 256, 0, stream>>>((const float4*)wih, wih_b, 393216u);
  conv_w_k<<<1024, 256, 0, stream>>>((const float4*)whh, whh_b, 262144u);
  gemm_xg<<<dim3(16, 256), 256, 0, stream>>>(xT_b, wih_b, bih, bhh, xg_b);
  lstm_rec<<<256, 256, 0, stream>>>(xg_b, whh_b, hbuf, out);
}

// Round 4
// 6772.553 us; speedup vs baseline: 3.7872x; 3.5715x over previous
//
#include <hip/hip_runtime.h>
#include <hip/hip_bf16.h>
#include <stdint.h>

typedef unsigned short ushort_t;
typedef unsigned int uint_t;
typedef unsigned long long ull_t;
typedef __attribute__((ext_vector_type(8))) short short8;
typedef __attribute__((ext_vector_type(4))) float floatx4;

#define T_STEPS 2048
#define BATCH 16
#define IN_F 768
#define HID 512
#define G4 2048   // 4*HID
#define NBLK 32   // phase-2 blocks

// ---------------- workspace layout (bytes) ----------------
static const size_t XG_OFF   = 0;                       // xg bf16 [T][16][2048]
static const size_t XT_OFF   = 134217728ull;            // xT bf16 [32768][768]
static const size_t WIH_OFF  = XT_OFF + 50331648ull;    // wih bf16 [2048][768]
static const size_t WHH_OFF  = WIH_OFF + 3145728ull;    // whh bf16 [2048][512]
static const size_t HBUF_OFF = WHH_OFF + 2097152ull;    // hbuf u32 [2][16][512] tagged
static const size_t WS_NEED  = HBUF_OFF + 65536ull;

// ---------------- helpers ----------------
__device__ inline ushort_t f2bf(float f) {
  uint_t u = __float_as_uint(f);
  u = (u + 0x7FFFu + ((u >> 16) & 1u)) >> 16;
  return (ushort_t)u;
}
__device__ inline float bf2f(ushort_t h) {
  return __uint_as_float(((uint_t)h) << 16);
}
__device__ inline floatx4 mfma16(short8 a, short8 b, floatx4 c) {
  return __builtin_amdgcn_mfma_f32_16x16x32_bf16(a, b, c, 0, 0, 0);
}
__device__ inline void ld_g2l16(const void* g, void* l) {
  __builtin_amdgcn_global_load_lds(
      (const __attribute__((address_space(1))) unsigned int*)g,
      (__attribute__((address_space(3))) unsigned int*)l, 16, 0, 0);
}
__device__ inline float sigf(float x) {
  float e = __expf(-x);
  return __fdividef(1.0f, 1.0f + e);
}
__device__ inline float tanhf_fast(float x) {
  x = fminf(fmaxf(x, -15.0f), 15.0f);
  float e = __expf(2.0f * x);
  return __fdividef(e - 1.0f, e + 1.0f);
}
// coherent (agent-scope) accesses — the PROVEN transport (4836us baseline)
__device__ inline ull_t cload64(const ull_t* p) {
  return __hip_atomic_load(p, __ATOMIC_RELAXED, __HIP_MEMORY_SCOPE_AGENT);
}
__device__ inline void cstore32(uint_t* p, uint_t v) {
  __hip_atomic_store(p, v, __ATOMIC_RELAXED, __HIP_MEMORY_SCOPE_AGENT);
}

// ---------------- phase 0: converts ----------------
__global__ __launch_bounds__(256) void conv_x_k(const float4* __restrict__ x,
                                                ushort_t* __restrict__ xT) {
  uint_t idx = blockIdx.x * 256u + threadIdx.x;  // < 6291456 exactly
  float4 v = x[idx];
  uint_t e = idx * 4u;
  uint_t k = e % 768u;
  uint_t rin = e / 768u;          // b*2048 + t
  uint_t b = rin >> 11, t = rin & 2047u;
  size_t o = (size_t)(t * 16u + b) * 768u + k;
  ushort4 r;
  r.x = f2bf(v.x); r.y = f2bf(v.y); r.z = f2bf(v.z); r.w = f2bf(v.w);
  *(ushort4*)(xT + o) = r;
}

__global__ __launch_bounds__(256) void conv_w_k(const float4* __restrict__ src,
                                                ushort_t* __restrict__ dst, uint_t n4) {
  uint_t idx = blockIdx.x * 256u + threadIdx.x;
  if (idx >= n4) return;
  float4 v = src[idx];
  ushort4 r;
  r.x = f2bf(v.x); r.y = f2bf(v.y); r.z = f2bf(v.z); r.w = f2bf(v.w);
  *(ushort4*)(dst + (size_t)idx * 4u) = r;
}

// ---------------- phase 1: xg = xT @ wih^T + bias, bf16 out ----------------
__global__ __launch_bounds__(256) void gemm_xg(const ushort_t* __restrict__ A,
                                               const ushort_t* __restrict__ Bw,
                                               const float* __restrict__ bih,
                                               const float* __restrict__ bhh,
                                               ushort_t* __restrict__ xg) {
  __shared__ __align__(16) ushort_t Asm[128 * 64];
  __shared__ __align__(16) ushort_t Bsm[128 * 64];
  const int tid = threadIdx.x;
  const int w = tid >> 6, l = tid & 63;
  const int m_ = l & 15, q = l >> 4;
  const int lr = l >> 3, lc = l & 7;
  const int nt = blockIdx.x, mt = blockIdx.y;
  const int wr = (w >> 1) * 64, wc = (w & 1) * 64;

  floatx4 acc[4][4];
  for (int i = 0; i < 4; i++)
    for (int j = 0; j < 4; j++) acc[i][j] = (floatx4){0.f, 0.f, 0.f, 0.f};

  for (int it = 0; it < 12; ++it) {
    const int K0 = it * 64;
    for (int p = 0; p < 4; p++) {
      int row = w * 32 + p * 8 + lr;
      int c = lc ^ lr;
      ld_g2l16(A + (size_t)(mt * 128 + row) * 768 + K0 + c * 8,
               Asm + (size_t)(w * 32 + p * 8) * 64);
      ld_g2l16(Bw + (size_t)(nt * 128 + row) * 768 + K0 + c * 8,
               Bsm + (size_t)(w * 32 + p * 8) * 64);
    }
    __syncthreads();
    short8 af[2][4], bfr[2][4];
    for (int kk = 0; kk < 2; kk++) {
      int chunk = kk * 4 + q;
      for (int rt = 0; rt < 4; rt++) {
        int row = wr + rt * 16 + m_;
        af[kk][rt] = *(const short8*)(Asm + (size_t)row * 64 + (size_t)(chunk ^ (row & 7)) * 8);
        int col = wc + rt * 16 + m_;
        bfr[kk][rt] = *(const short8*)(Bsm + (size_t)col * 64 + (size_t)(chunk ^ (col & 7)) * 8);
      }
    }
    for (int kk = 0; kk < 2; kk++)
      for (int rt = 0; rt < 4; rt++)
        for (int ct = 0; ct < 4; ct++)
          acc[rt][ct] = mfma16(af[kk][rt], bfr[kk][ct], acc[rt][ct]);
    __syncthreads();
  }
  for (int ct = 0; ct < 4; ct++) {
    int gcol = nt * 128 + wc + ct * 16 + m_;
    float bias = bih[gcol] + bhh[gcol];
    for (int rt = 0; rt < 4; rt++) {
      int growb = mt * 128 + wr + rt * 16 + q * 4;
      for (int r = 0; r < 4; r++)
        xg[(size_t)(growb + r) * G4 + gcol] = f2bf(acc[rt][ct][r] + bias);
    }
  }
}

// ---------------- phase 2: persistent recurrent kernel ----------------
// PROVEN 4836us structure: 32 blocks x 256 threads. Block j owns h cols
// [16j,16j+16). K-split: wave w reduces K in [128w,128w+128) for ALL 4 gates;
// partials summed via double-buffered gsm (one __syncthreads per step).
// h exchange: tagged u32 (tag<<16 | bf16), agent-scope. Producers
// store-and-go; consumers poll their own slice; a passing poll IS the data.
// Safety: tag t+2 in a buffer requires all blocks observed t+1 (double buffer)
// -> exact-match tag checks can never accept future data.
//
// NEW this round (poll-discovery latency only; transport untouched):
//  (a) 2-deep pipelined polling: two full 16-row sample sets in flight;
//      while checking one, the other is already issued (counted vmcnt).
//      Discovery granularity ~RTT -> ~RTT/2. Monotone exact-match tags make
//      a stale passing sample still-valid.
//  (b) early-issue: the first sample set for step t+1 is issued right after
//      publishing h(t+1), overlapping the first RTT with the step tail.
__global__ __launch_bounds__(256, 1) void lstm_rec(const ushort_t* __restrict__ xg,
                                                   const ushort_t* __restrict__ whh,
                                                   uint_t* hbuf, float* __restrict__ out) {
  const int tid = threadIdx.x;
  const int w = tid >> 6, l = tid & 63;
  const int m_ = l & 15, q = l >> 4;
  const int j = blockIdx.x;

  // bfrag[g][kk]: B[k][n], n = g*512 + j*16 + m_, k = w*128 + kk*32 + q*8 + jj
  short8 bfrag[4][4];
  for (int g = 0; g < 4; g++) {
    const ushort_t* wrow = whh + (size_t)(g * HID + j * 16 + m_) * HID + w * 128 + q * 8;
    for (int kk = 0; kk < 4; kk++) bfrag[g][kk] = *(const short8*)(wrow + kk * 32);
  }

  const int erow = tid >> 4, ecol = tid & 15;  // epilogue ownership (batch row, h col)
  float c_reg = 0.f;
  __shared__ __align__(16) ushort_t hsm[BATCH * HID];   // 16 KB, XOR-swizzled chunks
  __shared__ float gsm[2][4][4][16][17];                // [par][wave][gate][row][col]
  __shared__ uint_t s_dead;
  if (tid == 0) s_dead = 0u;
  __syncthreads();

  // epilogue xg: idx(t,g) = (t*16 + erow)*2048 + g*512 + j*16 + ecol
  const ushort_t* xgp = xg + (size_t)erow * G4 + j * 16 + ecol;
  ushort_t xgv[4];
  for (int g = 0; g < 4; g++) xgv[g] = xgp[g * HID];

  // stage: wave w loads tagged cols [128w,128w+128) of all 16 rows.
  // ull idx of lane l, row r: sbase + r*256 (row stride 512 u32).
  const ull_t* hb_ull = (const ull_t*)hbuf;
  const int sbase = w * 64 + l;
  uint_t guard = 0;
  bool dead = false;

  ull_t vA[16], vB[16];
  // strip tags + write own hsm slice (intra-wave only; conflict-free swizzle):
  // value pair = cols (128w + 2l, +1) of row r; chunk = 16w + (l>>2),
  // slot = chunk ^ (r&7), u32 offset (l&3) within 16B slot.
  const int chunk = w * 16 + (l >> 2);
  auto commit = [&](const ull_t (&v)[16]) {
#pragma unroll
    for (int r = 0; r < 16; r++) {
      uint_t pk = (uint_t)(v[r] & 0xffffu) | ((uint_t)(v[r] >> 32) << 16);
      int slot = chunk ^ (r & 7);
      *(uint_t*)(hsm + (size_t)r * HID + slot * 8 + (l & 3) * 2) = pk;
    }
  };

  // prologue: issue first sample set for t=0 (hbuf zeroed: tag 0 == h(0) == 0)
  {
    const ull_t* gp0 = hb_ull + sbase;
#pragma unroll
    for (int r = 0; r < 16; r++) vA[r] = cload64(gp0 + r * 256);
  }

  for (int t = 0; t < T_STEPS; t++) {
    // prefetch next step's xg (plain cached loads, independent of h)
    ushort_t xgn[4];
    {
      int tt = (t + 1 < T_STEPS) ? (t + 1) : t;
      const ushort_t* p = xgp + (size_t)tt * 16 * G4;
      for (int g = 0; g < 4; g++) xgn[g] = p[g * HID];
    }

    const ull_t* gp = hb_ull + (size_t)(t & 1) * 4096 + sbase;
    const ull_t expect = ((ull_t)(uint_t)(t & 0xffff) << 16) |
                         ((ull_t)(uint_t)(t & 0xffff) << 48);
    auto chk = [&](const ull_t (&v)[16]) {
      bool ok = true;
#pragma unroll
      for (int r = 0; r < 16; r++)
        ok &= ((v[r] & 0xFFFF0000FFFF0000ull) == expect);
      return __all((int)ok);
    };

    // ---- 2-deep pipelined poll: check one set while the other is in flight
    bool committed = false;
    if (!dead) {
      for (;;) {
#pragma unroll
        for (int r = 0; r < 16; r++) vB[r] = cload64(gp + r * 256);
        if (chk(vA)) { commit(vA); committed = true; break; }
        if (++guard > (1u << 20)) { dead = true; if (l == 0) s_dead = 1u; break; }
#pragma unroll
        for (int r = 0; r < 16; r++) vA[r] = cload64(gp + r * 256);
        if (chk(vB)) { commit(vB); committed = true; break; }
        if (++guard > (1u << 20)) { dead = true; if (l == 0) s_dead = 1u; break; }
      }
    }
    if (!committed) {
#pragma unroll
      for (int r = 0; r < 16; r++) vA[r] = 0;   // dead: zero h, keep lockstep
      commit(vA);
    }

    // ---- MFMA: A row m_, chunks 16w + kk*4 + q (own slice; in-wave ordering)
    floatx4 acc[4];
    for (int g = 0; g < 4; g++) acc[g] = (floatx4){0.f, 0.f, 0.f, 0.f};
    for (int kk = 0; kk < 4; kk++) {
      int slot = (w * 16 + kk * 4 + q) ^ (m_ & 7);
      short8 a = *(const short8*)(hsm + (size_t)m_ * HID + slot * 8);
      for (int g = 0; g < 4; g++) acc[g] = mfma16(a, bfrag[g][kk], acc[g]);
    }
    // ---- partial exchange ----
    const int par = t & 1;
    for (int g = 0; g < 4; g++)
      for (int r = 0; r < 4; r++) gsm[par][w][g][q * 4 + r][m_] = acc[g][r];
    __syncthreads();
    const bool blkdead = (s_dead != 0u);   // set pre-barrier by any dying wave
    if (blkdead) dead = true;

    float gate[4];
    for (int g = 0; g < 4; g++) {
      float s = gsm[par][0][g][erow][ecol] + gsm[par][1][g][erow][ecol] +
                gsm[par][2][g][erow][ecol] + gsm[par][3][g][erow][ecol];
      gate[g] = s + bf2f(xgv[g]);
    }
    float iv = sigf(gate[0]);
    float fv = sigf(gate[1]);
    float gv = tanhf_fast(gate[2]);
    float ov = sigf(gate[3]);
    float c = fv * c_reg + iv * gv;
    c_reg = c;
    float h = ov * tanhf_fast(c);

    if (!blkdead) {
      // ---- publish tagged h(t+1): store and go (critical path head) ----
      cstore32(hbuf + (size_t)((t + 1) & 1) * 8192 + (size_t)erow * HID + j * 16 + ecol,
               ((uint_t)((t + 1) & 0xffff) << 16) | (uint_t)f2bf(h));
    }

    // ---- early-issue first sample set for step t+1 (overlaps first RTT) ----
    if (!dead) {
      const ull_t* gpn = hb_ull + (size_t)((t + 1) & 1) * 4096 + sbase;
#pragma unroll
      for (int r = 0; r < 16; r++) vA[r] = cload64(gpn + r * 256);
    }

    if (!blkdead) {
      // off the critical path
      out[(size_t)erow * (T_STEPS * HID) + (size_t)t * HID + j * 16 + ecol] = h;
    }
    for (int g = 0; g < 4; g++) xgv[g] = xgn[g];
  }
}

// ---------------- host ----------------
extern "C" void kernel_launch(void* const* d_in, const int* in_sizes, int n_in,
                              void* d_out, int out_size, void* d_ws, size_t ws_size,
                              hipStream_t stream) {
  (void)in_sizes; (void)n_in; (void)out_size;
  if (ws_size < WS_NEED) return;

  const float* x   = (const float*)d_in[0];
  const float* wih = (const float*)d_in[1];
  const float* whh = (const float*)d_in[2];
  const float* bih = (const float*)d_in[3];
  const float* bhh = (const float*)d_in[4];
  float* out = (float*)d_out;
  char* ws = (char*)d_ws;

  ushort_t* xg_b   = (ushort_t*)(ws + XG_OFF);
  ushort_t* xT_b   = (ushort_t*)(ws + XT_OFF);
  ushort_t* wih_b  = (ushort_t*)(ws + WIH_OFF);
  ushort_t* whh_b  = (ushort_t*)(ws + WHH_OFF);
  uint_t*   hbuf   = (uint_t*)(ws + HBUF_OFF);

  // zero tagged h double-buffer: tag 0 == h(0) == 0
  hipMemsetAsync(ws + HBUF_OFF, 0, 65536, stream);

  conv_x_k<<<24576, 256, 0, stream>>>((const float4*)x, xT_b);
  conv_w_k<<<1536, 256, 0, stream>>>((const float4*)wih, wih_b, 393216u);
  conv_w_k<<<1024, 256, 0, stream>>>((const float4*)whh, whh_b, 262144u);
  gemm_xg<<<dim3(16, 256), 256, 0, stream>>>(xT_b, wih_b, bih, bhh, xg_b);
  lstm_rec<<<NBLK, 256, 0, stream>>>(xg_b, whh_b, hbuf, out);
}

// Round 5
// 5133.059 us; speedup vs baseline: 4.9969x; 1.3194x over previous
//
#include <hip/hip_runtime.h>
#include <hip/hip_bf16.h>
#include <stdint.h>

typedef unsigned short ushort_t;
typedef unsigned int uint_t;
typedef unsigned long long ull_t;
typedef __attribute__((ext_vector_type(8))) short short8;
typedef __attribute__((ext_vector_type(4))) float floatx4;

#define T_STEPS 2048
#define BATCH 16
#define IN_F 768
#define HID 512
#define G4 2048   // 4*HID
#define NBLK 32   // phase-2 blocks

// ---------------- workspace layout (bytes) ----------------
static const size_t XG_OFF   = 0;                       // xg bf16 [T][16][2048]
static const size_t XT_OFF   = 134217728ull;            // xT bf16 [32768][768]
static const size_t WIH_OFF  = XT_OFF + 50331648ull;    // wih bf16 [2048][768]
static const size_t WHH_OFF  = WIH_OFF + 3145728ull;    // whh bf16 [2048][512]
static const size_t HBUF_OFF = WHH_OFF + 2097152ull;    // hbuf u32 [2][16][512] tagged
static const size_t WS_NEED  = HBUF_OFF + 65536ull;

// ---------------- helpers ----------------
__device__ inline ushort_t f2bf(float f) {
  uint_t u = __float_as_uint(f);
  u = (u + 0x7FFFu + ((u >> 16) & 1u)) >> 16;
  return (ushort_t)u;
}
__device__ inline float bf2f(ushort_t h) {
  return __uint_as_float(((uint_t)h) << 16);
}
__device__ inline floatx4 mfma16(short8 a, short8 b, floatx4 c) {
  return __builtin_amdgcn_mfma_f32_16x16x32_bf16(a, b, c, 0, 0, 0);
}
__device__ inline void ld_g2l16(const void* g, void* l) {
  __builtin_amdgcn_global_load_lds(
      (const __attribute__((address_space(1))) unsigned int*)g,
      (__attribute__((address_space(3))) unsigned int*)l, 16, 0, 0);
}
__device__ inline float sigf(float x) {
  float e = __expf(-x);
  return __fdividef(1.0f, 1.0f + e);
}
__device__ inline float tanhf_fast(float x) {
  x = fminf(fmaxf(x, -15.0f), 15.0f);
  float e = __expf(2.0f * x);
  return __fdividef(e - 1.0f, e + 1.0f);
}
// coherent (agent-scope) accesses — the PROVEN transport (4836us baseline)
__device__ inline ull_t cload64(const ull_t* p) {
  return __hip_atomic_load(p, __ATOMIC_RELAXED, __HIP_MEMORY_SCOPE_AGENT);
}
__device__ inline void cstore32(uint_t* p, uint_t v) {
  __hip_atomic_store(p, v, __ATOMIC_RELAXED, __HIP_MEMORY_SCOPE_AGENT);
}

// ---------------- phase 0: converts ----------------
__global__ __launch_bounds__(256) void conv_x_k(const float4* __restrict__ x,
                                                ushort_t* __restrict__ xT) {
  uint_t idx = blockIdx.x * 256u + threadIdx.x;  // < 6291456 exactly
  float4 v = x[idx];
  uint_t e = idx * 4u;
  uint_t k = e % 768u;
  uint_t rin = e / 768u;          // b*2048 + t
  uint_t b = rin >> 11, t = rin & 2047u;
  size_t o = (size_t)(t * 16u + b) * 768u + k;
  ushort4 r;
  r.x = f2bf(v.x); r.y = f2bf(v.y); r.z = f2bf(v.z); r.w = f2bf(v.w);
  *(ushort4*)(xT + o) = r;
}

__global__ __launch_bounds__(256) void conv_w_k(const float4* __restrict__ src,
                                                ushort_t* __restrict__ dst, uint_t n4) {
  uint_t idx = blockIdx.x * 256u + threadIdx.x;
  if (idx >= n4) return;
  float4 v = src[idx];
  ushort4 r;
  r.x = f2bf(v.x); r.y = f2bf(v.y); r.z = f2bf(v.z); r.w = f2bf(v.w);
  *(ushort4*)(dst + (size_t)idx * 4u) = r;
}

// ---------------- phase 1: xg = xT @ wih^T + bias, bf16 out ----------------
__global__ __launch_bounds__(256) void gemm_xg(const ushort_t* __restrict__ A,
                                               const ushort_t* __restrict__ Bw,
                                               const float* __restrict__ bih,
                                               const float* __restrict__ bhh,
                                               ushort_t* __restrict__ xg) {
  __shared__ __align__(16) ushort_t Asm[128 * 64];
  __shared__ __align__(16) ushort_t Bsm[128 * 64];
  const int tid = threadIdx.x;
  const int w = tid >> 6, l = tid & 63;
  const int m_ = l & 15, q = l >> 4;
  const int lr = l >> 3, lc = l & 7;
  const int nt = blockIdx.x, mt = blockIdx.y;
  const int wr = (w >> 1) * 64, wc = (w & 1) * 64;

  floatx4 acc[4][4];
  for (int i = 0; i < 4; i++)
    for (int j = 0; j < 4; j++) acc[i][j] = (floatx4){0.f, 0.f, 0.f, 0.f};

  for (int it = 0; it < 12; ++it) {
    const int K0 = it * 64;
    for (int p = 0; p < 4; p++) {
      int row = w * 32 + p * 8 + lr;
      int c = lc ^ lr;
      ld_g2l16(A + (size_t)(mt * 128 + row) * 768 + K0 + c * 8,
               Asm + (size_t)(w * 32 + p * 8) * 64);
      ld_g2l16(Bw + (size_t)(nt * 128 + row) * 768 + K0 + c * 8,
               Bsm + (size_t)(w * 32 + p * 8) * 64);
    }
    __syncthreads();
    short8 af[2][4], bfr[2][4];
    for (int kk = 0; kk < 2; kk++) {
      int chunk = kk * 4 + q;
      for (int rt = 0; rt < 4; rt++) {
        int row = wr + rt * 16 + m_;
        af[kk][rt] = *(const short8*)(Asm + (size_t)row * 64 + (size_t)(chunk ^ (row & 7)) * 8);
        int col = wc + rt * 16 + m_;
        bfr[kk][rt] = *(const short8*)(Bsm + (size_t)col * 64 + (size_t)(chunk ^ (col & 7)) * 8);
      }
    }
    for (int kk = 0; kk < 2; kk++)
      for (int rt = 0; rt < 4; rt++)
        for (int ct = 0; ct < 4; ct++)
          acc[rt][ct] = mfma16(af[kk][rt], bfr[kk][ct], acc[rt][ct]);
    __syncthreads();
  }
  for (int ct = 0; ct < 4; ct++) {
    int gcol = nt * 128 + wc + ct * 16 + m_;
    float bias = bih[gcol] + bhh[gcol];
    for (int rt = 0; rt < 4; rt++) {
      int growb = mt * 128 + wr + rt * 16 + q * 4;
      for (int r = 0; r < 4; r++)
        xg[(size_t)(growb + r) * G4 + gcol] = f2bf(acc[rt][ct][r] + bias);
    }
  }
}

// ---------------- phase 2: persistent recurrent kernel ----------------
// PROVEN 4552us structure: 32 blocks x 256 threads. Block j owns h cols
// [16j,16j+16). K-split: wave w reduces K in [128w,128w+128) for ALL 4 gates;
// partials summed via double-buffered gsm (one __syncthreads per step).
// h exchange: tagged u32 (tag<<16 | bf16), agent-scope. Producers
// store-and-go; consumers poll their own slice; a passing poll IS the data.
// Safety: tag t+2 in a buffer requires all blocks observed t+1 (double buffer)
// -> exact-match tag checks can never accept future or stale data.
//
// NEW this round (poll-iteration cost only; transport & structure untouched):
//   Sparse sentinel pre-spin: lane l spins on ONE 8B tagged load at
//   (row l&15, its own col-pair). Across 64 lanes this samples all 16 rows
//   and all 8 producer blocks of the wave's slice at 1/16 the traffic
//   (512B/wave/probe vs 8KB) and single-load RTT granularity. On sentinel
//   pass: one full 16-row batch + exact-tag validation (sound per the
//   double-buffer invariant); validation failure just re-loops. Round-4
//   lesson applied: no speculative batches in flight across checks
//   (vmcnt(0)-drained checks serialize on the newest issue).
__global__ __launch_bounds__(256, 1) void lstm_rec(const ushort_t* __restrict__ xg,
                                                   const ushort_t* __restrict__ whh,
                                                   uint_t* hbuf, float* __restrict__ out) {
  const int tid = threadIdx.x;
  const int w = tid >> 6, l = tid & 63;
  const int m_ = l & 15, q = l >> 4;
  const int j = blockIdx.x;

  // bfrag[g][kk]: B[k][n], n = g*512 + j*16 + m_, k = w*128 + kk*32 + q*8 + jj
  short8 bfrag[4][4];
  for (int g = 0; g < 4; g++) {
    const ushort_t* wrow = whh + (size_t)(g * HID + j * 16 + m_) * HID + w * 128 + q * 8;
    for (int kk = 0; kk < 4; kk++) bfrag[g][kk] = *(const short8*)(wrow + kk * 32);
  }

  const int erow = tid >> 4, ecol = tid & 15;  // epilogue ownership (batch row, h col)
  float c_reg = 0.f;
  __shared__ __align__(16) ushort_t hsm[BATCH * HID];   // 16 KB, XOR-swizzled chunks
  __shared__ float gsm[2][4][4][16][17];                // [par][wave][gate][row][col]
  __shared__ uint_t s_dead;
  if (tid == 0) s_dead = 0u;
  __syncthreads();

  // epilogue xg: idx(t,g) = (t*16 + erow)*2048 + g*512 + j*16 + ecol
  const ushort_t* xgp = xg + (size_t)erow * G4 + j * 16 + ecol;
  ushort_t xgv[4];
  for (int g = 0; g < 4; g++) xgv[g] = xgp[g * HID];

  // stage: wave w loads tagged cols [128w,128w+128) of all 16 rows.
  // ull idx of lane l, row r: sbase + r*256 (row stride 512 u32).
  const ull_t* hb_ull = (const ull_t*)hbuf;
  const int sbase = w * 64 + l;
  const int srow = l & 15;            // sentinel row for this lane
  uint_t guard = 0;
  bool dead = false;

  for (int t = 0; t < T_STEPS; t++) {
    // prefetch next step's xg (plain cached loads, independent of h)
    ushort_t xgn[4];
    {
      int tt = (t + 1 < T_STEPS) ? (t + 1) : t;
      const ushort_t* p = xgp + (size_t)tt * 16 * G4;
      for (int g = 0; g < 4; g++) xgn[g] = p[g * HID];
    }

    // ---- poll + load own slice (tags == t) ----
    ull_t vals[16];
    {
      const ull_t* gp = hb_ull + (size_t)(t & 1) * 4096 + sbase;
      const ull_t* sp = gp + (size_t)srow * 256;    // sentinel cell
      const ull_t expect = ((ull_t)(uint_t)(t & 0xffff) << 16) |
                           ((ull_t)(uint_t)(t & 0xffff) << 48);
      bool got = false;
      while (!dead) {
        // 1-load sentinel spin (covers all 16 rows / all 8 producers per wave)
        ull_t sv = cload64(sp);
        if (__all((int)((sv & 0xFFFF0000FFFF0000ull) == expect))) {
          // full batch + exact-tag validation
          for (int r = 0; r < 16; r++) vals[r] = cload64(gp + r * 256);
          bool ok = true;
          for (int r = 0; r < 16; r++)
            ok &= ((vals[r] & 0xFFFF0000FFFF0000ull) == expect);
          if (__all((int)ok)) { got = true; break; }
        }
        if (++guard > (1u << 20)) { dead = true; if (l == 0) s_dead = 1u; }
      }
      if (!got) {
#pragma unroll
        for (int r = 0; r < 16; r++) vals[r] = 0;   // dead: zero h, keep lockstep
      }
    }

    // ---- strip tags, write own hsm slice (intra-wave only) ----
    // value pair = cols (128w + 2l, +1) of row r; chunk = 16w + (l>>2),
    // slot = chunk ^ (r&7), u32 offset (l&3) within 16B slot. Conflict-free.
    {
      const int chunk = w * 16 + (l >> 2);
      for (int r = 0; r < 16; r++) {
        uint_t pk = (uint_t)(vals[r] & 0xffffu) | ((uint_t)(vals[r] >> 32) << 16);
        int slot = chunk ^ (r & 7);
        *(uint_t*)(hsm + (size_t)r * HID + slot * 8 + (l & 3) * 2) = pk;
      }
    }
    // ---- MFMA: A row m_, chunks 16w + kk*4 + q (own slice; in-wave ordering) ----
    floatx4 acc[4];
    for (int g = 0; g < 4; g++) acc[g] = (floatx4){0.f, 0.f, 0.f, 0.f};
    for (int kk = 0; kk < 4; kk++) {
      int slot = (w * 16 + kk * 4 + q) ^ (m_ & 7);
      short8 a = *(const short8*)(hsm + (size_t)m_ * HID + slot * 8);
      for (int g = 0; g < 4; g++) acc[g] = mfma16(a, bfrag[g][kk], acc[g]);
    }
    // ---- partial exchange ----
    const int par = t & 1;
    for (int g = 0; g < 4; g++)
      for (int r = 0; r < 4; r++) gsm[par][w][g][q * 4 + r][m_] = acc[g][r];
    __syncthreads();
    const bool blkdead = (s_dead != 0u);   // set pre-barrier by any dying wave
    if (blkdead) dead = true;

    float gate[4];
    for (int g = 0; g < 4; g++) {
      float s = gsm[par][0][g][erow][ecol] + gsm[par][1][g][erow][ecol] +
                gsm[par][2][g][erow][ecol] + gsm[par][3][g][erow][ecol];
      gate[g] = s + bf2f(xgv[g]);
    }
    float iv = sigf(gate[0]);
    float fv = sigf(gate[1]);
    float gv = tanhf_fast(gate[2]);
    float ov = sigf(gate[3]);
    float c = fv * c_reg + iv * gv;
    c_reg = c;
    float h = ov * tanhf_fast(c);

    if (!blkdead) {
      // ---- publish tagged h(t+1): store and go (no drain, no flag) ----
      cstore32(hbuf + (size_t)((t + 1) & 1) * 8192 + (size_t)erow * HID + j * 16 + ecol,
               ((uint_t)((t + 1) & 0xffff) << 16) | (uint_t)f2bf(h));

      // off the critical path
      out[(size_t)erow * (T_STEPS * HID) + (size_t)t * HID + j * 16 + ecol] = h;
    }
    for (int g = 0; g < 4; g++) xgv[g] = xgn[g];
  }
}

// ---------------- host ----------------
extern "C" void kernel_launch(void* const* d_in, const int* in_sizes, int n_in,
                              void* d_out, int out_size, void* d_ws, size_t ws_size,
                              hipStream_t stream) {
  (void)in_sizes; (void)n_in; (void)out_size;
  if (ws_size < WS_NEED) return;

  const float* x   = (const float*)d_in[0];
  const float* wih = (const float*)d_in[1];
  const float* whh = (const float*)d_in[2];
  const float* bih = (const float*)d_in[3];
  const float* bhh = (const float*)d_in[4];
  float* out = (float*)d_out;
  char* ws = (char*)d_ws;

  ushort_t* xg_b   = (ushort_t*)(ws + XG_OFF);
  ushort_t* xT_b   = (ushort_t*)(ws + XT_OFF);
  ushort_t* wih_b  = (ushort_t*)(ws + WIH_OFF);
  ushort_t* whh_b  = (ushort_t*)(ws + WHH_OFF);
  uint_t*   hbuf   = (uint_t*)(ws + HBUF_OFF);

  // zero tagged h double-buffer: tag 0 == h(0) == 0 (ws poisoned each call)
  hipMemsetAsync(ws + HBUF_OFF, 0, 65536, stream);

  conv_x_k<<<24576, 256, 0, stream>>>((const float4*)x, xT_b);
  conv_w_k<<<1536, 256, 0, stream>>>((const float4*)wih, wih_b, 393216u);
  conv_w_k<<<1024, 256, 0, stream>>>((const float4*)whh, whh_b, 262144u);
  gemm_xg<<<dim3(16, 256), 256, 0, stream>>>(xT_b, wih_b, bih, bhh, xg_b);
  lstm_rec<<<NBLK, 256, 0, stream>>>(xg_b, whh_b, hbuf, out);
}

// Round 6
// 4750.049 us; speedup vs baseline: 5.3998x; 1.0806x over previous
//
#include <hip/hip_runtime.h>
#include <hip/hip_bf16.h>
#include <stdint.h>

typedef unsigned short ushort_t;
typedef unsigned int uint_t;
typedef unsigned long long ull_t;
typedef __attribute__((ext_vector_type(8))) short short8;
typedef __attribute__((ext_vector_type(4))) float floatx4;

#define T_STEPS 2048
#define BATCH 16
#define IN_F 768
#define HID 512
#define G4 2048   // 4*HID
#define NBLK 32   // phase-2 blocks

// ---------------- workspace layout (bytes) ----------------
static const size_t XG_OFF   = 0;                       // xg bf16 [T][16][2048]
static const size_t XT_OFF   = 134217728ull;            // xT bf16 [32768][768]
static const size_t WIH_OFF  = XT_OFF + 50331648ull;    // wih bf16 [2048][768]
static const size_t WHH_OFF  = WIH_OFF + 3145728ull;    // whh bf16 [2048][512]
static const size_t HBUF_OFF = WHH_OFF + 2097152ull;    // hbuf u32 [2][16][512] tagged
static const size_t WS_NEED  = HBUF_OFF + 65536ull;

// ---------------- helpers ----------------
__device__ inline ushort_t f2bf(float f) {
  uint_t u = __float_as_uint(f);
  u = (u + 0x7FFFu + ((u >> 16) & 1u)) >> 16;
  return (ushort_t)u;
}
__device__ inline float bf2f(ushort_t h) {
  return __uint_as_float(((uint_t)h) << 16);
}
__device__ inline floatx4 mfma16(short8 a, short8 b, floatx4 c) {
  return __builtin_amdgcn_mfma_f32_16x16x32_bf16(a, b, c, 0, 0, 0);
}
__device__ inline void ld_g2l16(const void* g, void* l) {
  __builtin_amdgcn_global_load_lds(
      (const __attribute__((address_space(1))) unsigned int*)g,
      (__attribute__((address_space(3))) unsigned int*)l, 16, 0, 0);
}
__device__ inline float sigf(float x) {
  float e = __expf(-x);
  return __fdividef(1.0f, 1.0f + e);
}
__device__ inline float tanhf_fast(float x) {
  x = fminf(fmaxf(x, -15.0f), 15.0f);
  float e = __expf(2.0f * x);
  return __fdividef(e - 1.0f, e + 1.0f);
}
// coherent (agent-scope) accesses — the PROVEN transport (4552us baseline)
__device__ inline ull_t cload64(const ull_t* p) {
  return __hip_atomic_load(p, __ATOMIC_RELAXED, __HIP_MEMORY_SCOPE_AGENT);
}
__device__ inline void cstore32(uint_t* p, uint_t v) {
  __hip_atomic_store(p, v, __ATOMIC_RELAXED, __HIP_MEMORY_SCOPE_AGENT);
}

// ---------------- phase 0: converts ----------------
__global__ __launch_bounds__(256) void conv_x_k(const float4* __restrict__ x,
                                                ushort_t* __restrict__ xT) {
  uint_t idx = blockIdx.x * 256u + threadIdx.x;  // < 6291456 exactly
  float4 v = x[idx];
  uint_t e = idx * 4u;
  uint_t k = e % 768u;
  uint_t rin = e / 768u;          // b*2048 + t
  uint_t b = rin >> 11, t = rin & 2047u;
  size_t o = (size_t)(t * 16u + b) * 768u + k;
  ushort4 r;
  r.x = f2bf(v.x); r.y = f2bf(v.y); r.z = f2bf(v.z); r.w = f2bf(v.w);
  *(ushort4*)(xT + o) = r;
}

__global__ __launch_bounds__(256) void conv_w_k(const float4* __restrict__ src,
                                                ushort_t* __restrict__ dst, uint_t n4) {
  uint_t idx = blockIdx.x * 256u + threadIdx.x;
  if (idx >= n4) return;
  float4 v = src[idx];
  ushort4 r;
  r.x = f2bf(v.x); r.y = f2bf(v.y); r.z = f2bf(v.z); r.w = f2bf(v.w);
  *(ushort4*)(dst + (size_t)idx * 4u) = r;
}

// ---------------- phase 1: xg = xT @ wih^T + bias, bf16 out ----------------
__global__ __launch_bounds__(256) void gemm_xg(const ushort_t* __restrict__ A,
                                               const ushort_t* __restrict__ Bw,
                                               const float* __restrict__ bih,
                                               const float* __restrict__ bhh,
                                               ushort_t* __restrict__ xg) {
  __shared__ __align__(16) ushort_t Asm[128 * 64];
  __shared__ __align__(16) ushort_t Bsm[128 * 64];
  const int tid = threadIdx.x;
  const int w = tid >> 6, l = tid & 63;
  const int m_ = l & 15, q = l >> 4;
  const int lr = l >> 3, lc = l & 7;
  const int nt = blockIdx.x, mt = blockIdx.y;
  const int wr = (w >> 1) * 64, wc = (w & 1) * 64;

  floatx4 acc[4][4];
  for (int i = 0; i < 4; i++)
    for (int j = 0; j < 4; j++) acc[i][j] = (floatx4){0.f, 0.f, 0.f, 0.f};

  for (int it = 0; it < 12; ++it) {
    const int K0 = it * 64;
    for (int p = 0; p < 4; p++) {
      int row = w * 32 + p * 8 + lr;
      int c = lc ^ lr;
      ld_g2l16(A + (size_t)(mt * 128 + row) * 768 + K0 + c * 8,
               Asm + (size_t)(w * 32 + p * 8) * 64);
      ld_g2l16(Bw + (size_t)(nt * 128 + row) * 768 + K0 + c * 8,
               Bsm + (size_t)(w * 32 + p * 8) * 64);
    }
    __syncthreads();
    short8 af[2][4], bfr[2][4];
    for (int kk = 0; kk < 2; kk++) {
      int chunk = kk * 4 + q;
      for (int rt = 0; rt < 4; rt++) {
        int row = wr + rt * 16 + m_;
        af[kk][rt] = *(const short8*)(Asm + (size_t)row * 64 + (size_t)(chunk ^ (row & 7)) * 8);
        int col = wc + rt * 16 + m_;
        bfr[kk][rt] = *(const short8*)(Bsm + (size_t)col * 64 + (size_t)(chunk ^ (col & 7)) * 8);
      }
    }
    for (int kk = 0; kk < 2; kk++)
      for (int rt = 0; rt < 4; rt++)
        for (int ct = 0; ct < 4; ct++)
          acc[rt][ct] = mfma16(af[kk][rt], bfr[kk][ct], acc[rt][ct]);
    __syncthreads();
  }
  for (int ct = 0; ct < 4; ct++) {
    int gcol = nt * 128 + wc + ct * 16 + m_;
    float bias = bih[gcol] + bhh[gcol];
    for (int rt = 0; rt < 4; rt++) {
      int growb = mt * 128 + wr + rt * 16 + q * 4;
      for (int r = 0; r < 4; r++)
        xg[(size_t)(growb + r) * G4 + gcol] = f2bf(acc[rt][ct][r] + bias);
    }
  }
}

// ---------------- phase 2: persistent recurrent kernel ----------------
// PROVEN 4552us structure: 32 blocks x 256 threads. Block j owns h cols
// [16j,16j+16). K-split: wave w reduces K in [128w,128w+128) for ALL 4 gates;
// partials summed via double-buffered gsm (one __syncthreads per step).
// h exchange: tagged u32 (tag<<16 | bf16), agent-scope. Producers
// store-and-go; consumers poll their own slice; a passing poll IS the data
// (discovery + payload in ONE batch RTT — rounds 4/5 proved splitting or
// pipelining this loses).
//
// NEW this round (single variable): bounded BACKOFF in the poll loop.
// After each failed check, s_sleep(2) (~128cy). Theory: 128 waves
// continuously re-issuing 8KB poll batches against the 64KB hbuf region
// saturates its few MALL slices; producer stores queue behind the polls,
// stretching visibility. Backoff cuts poll pressure during the store-
// propagation window. Cost ceiling if theory wrong: ~64cy/step (~0.03us).
__global__ __launch_bounds__(256, 1) void lstm_rec(const ushort_t* __restrict__ xg,
                                                   const ushort_t* __restrict__ whh,
                                                   uint_t* hbuf, float* __restrict__ out) {
  const int tid = threadIdx.x;
  const int w = tid >> 6, l = tid & 63;
  const int m_ = l & 15, q = l >> 4;
  const int j = blockIdx.x;

  // bfrag[g][kk]: B[k][n], n = g*512 + j*16 + m_, k = w*128 + kk*32 + q*8 + jj
  short8 bfrag[4][4];
  for (int g = 0; g < 4; g++) {
    const ushort_t* wrow = whh + (size_t)(g * HID + j * 16 + m_) * HID + w * 128 + q * 8;
    for (int kk = 0; kk < 4; kk++) bfrag[g][kk] = *(const short8*)(wrow + kk * 32);
  }

  const int erow = tid >> 4, ecol = tid & 15;  // epilogue ownership (batch row, h col)
  float c_reg = 0.f;
  __shared__ __align__(16) ushort_t hsm[BATCH * HID];   // 16 KB, XOR-swizzled chunks
  __shared__ float gsm[2][4][4][16][17];                // [par][wave][gate][row][col]
  __shared__ uint_t s_dead;
  if (tid == 0) s_dead = 0u;
  __syncthreads();

  // epilogue xg: idx(t,g) = (t*16 + erow)*2048 + g*512 + j*16 + ecol
  const ushort_t* xgp = xg + (size_t)erow * G4 + j * 16 + ecol;
  ushort_t xgv[4];
  for (int g = 0; g < 4; g++) xgv[g] = xgp[g * HID];

  // stage: wave w loads tagged cols [128w,128w+128) of all 16 rows.
  // ull idx of lane l, row r: sbase + r*256 (row stride 512 u32).
  const ull_t* hb_ull = (const ull_t*)hbuf;
  const int sbase = w * 64 + l;
  uint_t guard = 0;
  bool dead = false;

  for (int t = 0; t < T_STEPS; t++) {
    // prefetch next step's xg (plain cached loads, independent of h)
    ushort_t xgn[4];
    {
      int tt = (t + 1 < T_STEPS) ? (t + 1) : t;
      const ushort_t* p = xgp + (size_t)tt * 16 * G4;
      for (int g = 0; g < 4; g++) xgn[g] = p[g * HID];
    }

    // ---- poll + load own slice (tags == t) ----
    ull_t vals[16];
    {
      const ull_t* gp = hb_ull + (size_t)(t & 1) * 4096 + sbase;
      const ull_t expect = ((ull_t)(uint_t)(t & 0xffff) << 16) |
                           ((ull_t)(uint_t)(t & 0xffff) << 48);
      bool got = false;
      while (!dead) {
        for (int r = 0; r < 16; r++) vals[r] = cload64(gp + r * 256);
        bool ok = true;
        for (int r = 0; r < 16; r++)
          ok &= ((vals[r] & 0xFFFF0000FFFF0000ull) == expect);
        if (__all((int)ok)) { got = true; break; }
        if (++guard > (1u << 20)) { dead = true; if (l == 0) s_dead = 1u; break; }
        __builtin_amdgcn_s_sleep(2);   // ~128cy backoff: relieve MALL-slice pressure
      }
      if (!got) {
#pragma unroll
        for (int r = 0; r < 16; r++) vals[r] = 0;   // dead: zero h, keep lockstep
      }
    }

    // ---- strip tags, write own hsm slice (intra-wave only) ----
    // value pair = cols (128w + 2l, +1) of row r; chunk = 16w + (l>>2),
    // slot = chunk ^ (r&7), u32 offset (l&3) within 16B slot. Conflict-free.
    {
      const int chunk = w * 16 + (l >> 2);
      for (int r = 0; r < 16; r++) {
        uint_t pk = (uint_t)(vals[r] & 0xffffu) | ((uint_t)(vals[r] >> 32) << 16);
        int slot = chunk ^ (r & 7);
        *(uint_t*)(hsm + (size_t)r * HID + slot * 8 + (l & 3) * 2) = pk;
      }
    }
    // ---- MFMA: A row m_, chunks 16w + kk*4 + q (own slice; in-wave ordering) ----
    floatx4 acc[4];
    for (int g = 0; g < 4; g++) acc[g] = (floatx4){0.f, 0.f, 0.f, 0.f};
    for (int kk = 0; kk < 4; kk++) {
      int slot = (w * 16 + kk * 4 + q) ^ (m_ & 7);
      short8 a = *(const short8*)(hsm + (size_t)m_ * HID + slot * 8);
      for (int g = 0; g < 4; g++) acc[g] = mfma16(a, bfrag[g][kk], acc[g]);
    }
    // ---- partial exchange ----
    const int par = t & 1;
    for (int g = 0; g < 4; g++)
      for (int r = 0; r < 4; r++) gsm[par][w][g][q * 4 + r][m_] = acc[g][r];
    __syncthreads();
    const bool blkdead = (s_dead != 0u);   // set pre-barrier by any dying wave
    if (blkdead) dead = true;

    float gate[4];
    for (int g = 0; g < 4; g++) {
      float s = gsm[par][0][g][erow][ecol] + gsm[par][1][g][erow][ecol] +
                gsm[par][2][g][erow][ecol] + gsm[par][3][g][erow][ecol];
      gate[g] = s + bf2f(xgv[g]);
    }
    float iv = sigf(gate[0]);
    float fv = sigf(gate[1]);
    float gv = tanhf_fast(gate[2]);
    float ov = sigf(gate[3]);
    float c = fv * c_reg + iv * gv;
    c_reg = c;
    float h = ov * tanhf_fast(c);

    if (!blkdead) {
      // ---- publish tagged h(t+1): store and go (no drain, no flag) ----
      cstore32(hbuf + (size_t)((t + 1) & 1) * 8192 + (size_t)erow * HID + j * 16 + ecol,
               ((uint_t)((t + 1) & 0xffff) << 16) | (uint_t)f2bf(h));

      // off the critical path
      out[(size_t)erow * (T_STEPS * HID) + (size_t)t * HID + j * 16 + ecol] = h;
    }
    for (int g = 0; g < 4; g++) xgv[g] = xgn[g];
  }
}

// ---------------- host ----------------
extern "C" void kernel_launch(void* const* d_in, const int* in_sizes, int n_in,
                              void* d_out, int out_size, void* d_ws, size_t ws_size,
                              hipStream_t stream) {
  (void)in_sizes; (void)n_in; (void)out_size;
  if (ws_size < WS_NEED) return;

  const float* x   = (const float*)d_in[0];
  const float* wih = (const float*)d_in[1];
  const float* whh = (const float*)d_in[2];
  const float* bih = (const float*)d_in[3];
  const float* bhh = (const float*)d_in[4];
  float* out = (float*)d_out;
  char* ws = (char*)d_ws;

  ushort_t* xg_b   = (ushort_t*)(ws + XG_OFF);
  ushort_t* xT_b   = (ushort_t*)(ws + XT_OFF);
  ushort_t* wih_b  = (ushort_t*)(ws + WIH_OFF);
  ushort_t* whh_b  = (ushort_t*)(ws + WHH_OFF);
  uint_t*   hbuf   = (uint_t*)(ws + HBUF_OFF);

  // zero tagged h double-buffer: tag 0 == h(0) == 0 (ws poisoned each call)
  hipMemsetAsync(ws + HBUF_OFF, 0, 65536, stream);

  conv_x_k<<<24576, 256, 0, stream>>>((const float4*)x, xT_b);
  conv_w_k<<<1536, 256, 0, stream>>>((const float4*)wih, wih_b, 393216u);
  conv_w_k<<<1024, 256, 0, stream>>>((const float4*)whh, whh_b, 262144u);
  gemm_xg<<<dim3(16, 256), 256, 0, stream>>>(xT_b, wih_b, bih, bhh, xg_b);
  lstm_rec<<<NBLK, 256, 0, stream>>>(xg_b, whh_b, hbuf, out);
}